// Round 3
// baseline (1685.785 us; speedup 1.0000x reference)
//
#include <hip/hip_runtime.h>

typedef _Float16 h2 __attribute__((ext_vector_type(2)));

#define MAT_N 256
#define MAT_ELEMS (MAT_N * MAT_N)
#define NUM_ITERS 20

// ---- cross-lane helpers (VALU DPP + ds_swizzle) -------------------------
template<int CTRL>
__device__ __forceinline__ float dpp_add(float x) {
    int i = __builtin_bit_cast(int, x);
    int r = __builtin_amdgcn_update_dpp(i, i, CTRL, 0xF, 0xF, true);
    return x + __builtin_bit_cast(float, r);
}
__device__ __forceinline__ float swz16_add(float x) {   // xor16 within 32 lanes
    int i = __builtin_bit_cast(int, x);
    int r = __builtin_amdgcn_ds_swizzle(i, 0x401F);
    return x + __builtin_bit_cast(float, r);
}
// Reduce across the 32 lanes sharing R; result in every lane.
__device__ __forceinline__ float half32_reduce(float x) {
    x = dpp_add<0xB1>(x);    // xor1
    x = dpp_add<0x4E>(x);    // xor2
    x = dpp_add<0x141>(x);   // half mirror (xor4)
    x = dpp_add<0x140>(x);   // mirror (xor8)
    x = swz16_add(x);        // xor16
    return x;
}

__device__ __forceinline__ float dot2(h2 a, h2 b, float c) {
#if __has_builtin(__builtin_amdgcn_fdot2)
    return __builtin_amdgcn_fdot2(a, b, c, false);
#else
    return fmaf((float)a.x, (float)b.x, fmaf((float)a.y, (float)b.y, c));
#endif
}

// One 1024-thread block per matrix, 2 blocks/CU resident.
// Thread (R=tid>>5, C=tid&31) owns rows 8R..8R+7, cols {4C..4C+3, 128+4C..128+4C+3}
// packed as 4 f16 pairs per row.
__global__ __launch_bounds__(1024, 8) void sinkhorn_kernel(
        const float* __restrict__ in, float* __restrict__ out) {
    const int tid = threadIdx.x;
    const int R = tid >> 5;      // 0..31
    const int C = tid & 31;
    const int w = tid >> 6;      // wave id 0..15
    const int lane = tid & 63;

    __shared__ __align__(16) float Q1[16][260];  // col partials: [wave][col], 16.6 KB
    __shared__ float Vc[256];                    // col reciprocals

    const size_t base = (size_t)blockIdx.x * MAT_ELEMS;
    const float4* __restrict__ in4 = (const float4*)(in + base);
    float4* __restrict__ out4 = (float4*)(out + base);

    // ---- load + exp -> f16 packed ----
    h2 qp[8][4];
    #pragma unroll
    for (int i = 0; i < 8; ++i) {
        #pragma unroll
        for (int d = 0; d < 2; ++d) {
            float4 t = in4[(8 * R + i) * 64 + C + 32 * d];
            h2 a, b;
            a.x = (_Float16)__expf(t.x); a.y = (_Float16)__expf(t.y);
            b.x = (_Float16)__expf(t.z); b.y = (_Float16)__expf(t.w);
            qp[i][2 * d] = a; qp[i][2 * d + 1] = b;
        }
    }

    h2 vp[4];
    {
        h2 one; one.x = (_Float16)1.f; one.y = (_Float16)1.f;
        vp[0] = one; vp[1] = one; vp[2] = one; vp[3] = one;
    }
    float u[8];

    #pragma unroll 1
    for (int it = 0; it < NUM_ITERS; ++it) {
        // ---- row phase: u = 1/(M v), in-wave ----
        #pragma unroll
        for (int i = 0; i < 8; ++i) {
            float s = dot2(qp[i][0], vp[0], 0.f);
            s = dot2(qp[i][1], vp[1], s);
            s = dot2(qp[i][2], vp[2], s);
            s = dot2(qp[i][3], vp[3], s);
            s = half32_reduce(s);
            u[i] = __builtin_amdgcn_rcpf(s);
        }

        // ---- col phase: v = 1/(M^T u) ----
        float cs[8];
        #pragma unroll
        for (int j = 0; j < 8; ++j) {
            const int p = j >> 1;
            float s = 0.f;
            #pragma unroll
            for (int i = 0; i < 8; ++i) {
                float qf = (j & 1) ? (float)qp[i][p].y : (float)qp[i][p].x;
                s = fmaf(qf, u[i], s);   // mad-mix pattern
            }
            cs[j] = s;
        }
        // pre-reduce across the wave's two R-groups (rows 16w..16w+15)
        #pragma unroll
        for (int j = 0; j < 8; ++j) cs[j] += __shfl_xor(cs[j], 32);
        if (lane < 32) {
            *(float4*)&Q1[w][4 * C]       = make_float4(cs[0], cs[1], cs[2], cs[3]);
            *(float4*)&Q1[w][4 * C + 128] = make_float4(cs[4], cs[5], cs[6], cs[7]);
        }
        __syncthreads();

        {   // 4 threads per column: 4 reads + quad DPP reduce
            const int col = tid >> 2;
            const int r0 = (tid & 3) * 4;
            float s = (Q1[r0][col] + Q1[r0 + 1][col]) +
                      (Q1[r0 + 2][col] + Q1[r0 + 3][col]);
            s = dpp_add<0xB1>(s);
            s = dpp_add<0x4E>(s);
            if ((tid & 3) == 0) Vc[col] = __builtin_amdgcn_rcpf(s);
        }
        __syncthreads();

        {   // reload v as f16 pairs
            float4 a = *(const float4*)&Vc[4 * C];
            float4 b = *(const float4*)&Vc[4 * C + 128];
            h2 t;
            t.x = (_Float16)a.x; t.y = (_Float16)a.y; vp[0] = t;
            t.x = (_Float16)a.z; t.y = (_Float16)a.w; vp[1] = t;
            t.x = (_Float16)b.x; t.y = (_Float16)b.y; vp[2] = t;
            t.x = (_Float16)b.z; t.y = (_Float16)b.w; vp[3] = t;
        }
    }

    // ---- store: out = u_i * q_ij * v_j (f32) ----
    float vf[8];
    #pragma unroll
    for (int p = 0; p < 4; ++p) {
        vf[2 * p]     = (float)vp[p].x;
        vf[2 * p + 1] = (float)vp[p].y;
    }
    #pragma unroll
    for (int i = 0; i < 8; ++i) {
        const float s = u[i];
        float4 o0, o1;
        o0.x = (float)qp[i][0].x * (s * vf[0]);
        o0.y = (float)qp[i][0].y * (s * vf[1]);
        o0.z = (float)qp[i][1].x * (s * vf[2]);
        o0.w = (float)qp[i][1].y * (s * vf[3]);
        o1.x = (float)qp[i][2].x * (s * vf[4]);
        o1.y = (float)qp[i][2].y * (s * vf[5]);
        o1.z = (float)qp[i][3].x * (s * vf[6]);
        o1.w = (float)qp[i][3].y * (s * vf[7]);
        out4[(8 * R + i) * 64 + C]      = o0;
        out4[(8 * R + i) * 64 + C + 32] = o1;
    }
}

extern "C" void kernel_launch(void* const* d_in, const int* in_sizes, int n_in,
                              void* d_out, int out_size, void* d_ws, size_t ws_size,
                              hipStream_t stream) {
    const float* in = (const float*)d_in[0];
    float* out = (float*)d_out;
    const int nmat = in_sizes[0] / MAT_ELEMS;  // 2048
    sinkhorn_kernel<<<nmat, 1024, 0, stream>>>(in, out);
}